// Round 12
// baseline (307.590 us; speedup 1.0000x reference)
//
#include <hip/hip_runtime.h>
#include <limits.h>
#include <cstdint>

typedef __bf16 bf16_t;
typedef __attribute__((ext_vector_type(8))) __bf16 bf16x8;
typedef __attribute__((ext_vector_type(4))) float f32x4;
typedef __attribute__((ext_vector_type(2))) float f32x2;

#define CH 64     // edges per wave in edge_stream

__device__ __forceinline__ float rlf(float v, int l) {
  return __int_as_float(__builtin_amdgcn_readlane(__float_as_int(v), l));
}

// ---------------------------------------------------------------------------
// ONE prep kernel (137 blocks x 256):
//  blocks 0..127 : pack Wt0 = Wb0[0:128,:] and Wt1 = Wb1[0:128,:] -> B-frag bf16
//  blocks 128..135: W' = Wo0 @ Wb1[0:128,:]  (128x128 fp32 dot) packed directly
//  block 136     : bb1'[n] = bb1[n] + bo0 . Wb1[:,n] ;
//                  wf0'[k] = Wo0[k,:] . Wf ; wf1'[k] = Wo1[k,:] . Wf ;
//                  c = bf + (bo0+bo1) . Wf
// packed[((kt*8+nt)*64+L)*8+j] = W[kt*32+(L>>4)*8+j][nt*16+(L&15)]
// ---------------------------------------------------------------------------
struct PrepArgs {
  const float *Wb0, *Wb1, *Wo0, *Wo1, *Wf, *bb1, *bo0, *bo1, *bf;
  bf16_t *Wt0pk, *Wt1pk, *Wppk;
  float *bb1p, *wf0p, *wf1p, *cp;
};

__global__ __launch_bounds__(256) void prep_kernel(PrepArgs a) {
  const int blk = blockIdx.x;
  const int tid = threadIdx.x;
  if (blk < 128) {
    int idx = blk * 256 + tid;            // < 32768
    int which = idx >> 14;
    int r = idx & 16383;
    int j  = r & 7;
    int L  = (r >> 3) & 63;
    int nt = (r >> 9) & 7;
    int kt = r >> 12;
    int k = kt * 32 + (L >> 4) * 8 + j;
    int n = nt * 16 + (L & 15);
    const float* W = which ? a.Wb1 : a.Wb0;
    bf16_t* P = which ? a.Wt1pk : a.Wt0pk;
    P[r] = (bf16_t)W[(size_t)k * 128 + n];
  } else if (blk < 136) {
    int t = (blk - 128) * 256 + tid;      // < 2048; thread -> 8 outputs (j)
    int L  = t & 63;
    int nt = (t >> 6) & 7;
    int kt = t >> 9;
    int n = nt * 16 + (L & 15);
    int kbase = kt * 32 + (L >> 4) * 8;
    float acc[8];
    #pragma unroll
    for (int j = 0; j < 8; ++j) acc[j] = 0.f;
    for (int m = 0; m < 128; ++m) {
      float w1 = a.Wb1[(size_t)m * 128 + n];
      #pragma unroll
      for (int j = 0; j < 8; ++j)
        acc[j] += a.Wo0[(size_t)(kbase + j) * 128 + m] * w1;
    }
    #pragma unroll
    for (int j = 0; j < 8; ++j) a.Wppk[(size_t)t * 8 + j] = (bf16_t)acc[j];
  } else {
    if (tid < 128) {
      int n = tid;
      float s = 0.f;
      for (int k = 0; k < 128; ++k) s += a.bo0[k] * a.Wb1[(size_t)k * 128 + n];
      a.bb1p[n] = a.bb1[n] + s;
      float s0 = 0.f, s1 = 0.f;
      for (int m = 0; m < 128; ++m) {
        s0 += a.Wo0[(size_t)n * 128 + m] * a.Wf[m];
        s1 += a.Wo1[(size_t)n * 128 + m] * a.Wf[m];
      }
      a.wf0p[n] = s0;
      a.wf1p[n] = s1;
      if (n == 0) {
        float c = a.bf[0];
        for (int m = 0; m < 128; ++m) c += (a.bo0[m] + a.bo1[m]) * a.Wf[m];
        a.cp[0] = c;
      }
    }
  }
}

// ---------------------------------------------------------------------------
// Y0 = interp @ Wt0 via bf16 MFMA (fp32 in-register convert); zeroes pooled0.
// ---------------------------------------------------------------------------
__global__ __launch_bounds__(256, 4) void yproj_f32(
    const float* __restrict__ X, const bf16_t* __restrict__ Wtpk,
    bf16_t* __restrict__ Ybf, float* __restrict__ pooled, int N)
{
  const int tid = threadIdx.x;
  const int base = blockIdx.x * 128;

  float4 z = make_float4(0.f, 0.f, 0.f, 0.f);
  #pragma unroll
  for (int i = 0; i < 16; ++i) {
    int idx = tid + i * 256;
    int row = base + (idx >> 5);
    if (row < N)
      reinterpret_cast<float4*>(pooled)[(size_t)row * 32 + (idx & 31)] = z;
  }

  const int lane = tid & 63;
  const int w    = tid >> 6;
  const int q    = lane >> 4;
  const int ln   = lane & 15;
  const int n0   = base + w * 32;

  int r0 = n0 + ln, r1 = n0 + 16 + ln;
  int r0c = (r0 < N) ? r0 : (N - 1);
  int r1c = (r1 < N) ? r1 : (N - 1);
  const float* x0 = X + (size_t)r0c * 128 + q * 8;
  const float* x1 = X + (size_t)r1c * 128 + q * 8;

  f32x4 acc[2][8];
  #pragma unroll
  for (int mt = 0; mt < 2; ++mt)
    #pragma unroll
    for (int nt = 0; nt < 8; ++nt)
      #pragma unroll
      for (int r = 0; r < 4; ++r) acc[mt][nt][r] = 0.f;

  const bf16x8* Wp = reinterpret_cast<const bf16x8*>(Wtpk);
  #pragma unroll
  for (int kt = 0; kt < 4; ++kt) {
    float4 f0a = *reinterpret_cast<const float4*>(x0 + kt * 32);
    float4 f0b = *reinterpret_cast<const float4*>(x0 + kt * 32 + 4);
    float4 f1a = *reinterpret_cast<const float4*>(x1 + kt * 32);
    float4 f1b = *reinterpret_cast<const float4*>(x1 + kt * 32 + 4);
    bf16x8 a0, a1;
    a0[0] = (bf16_t)f0a.x; a0[1] = (bf16_t)f0a.y; a0[2] = (bf16_t)f0a.z; a0[3] = (bf16_t)f0a.w;
    a0[4] = (bf16_t)f0b.x; a0[5] = (bf16_t)f0b.y; a0[6] = (bf16_t)f0b.z; a0[7] = (bf16_t)f0b.w;
    a1[0] = (bf16_t)f1a.x; a1[1] = (bf16_t)f1a.y; a1[2] = (bf16_t)f1a.z; a1[3] = (bf16_t)f1a.w;
    a1[4] = (bf16_t)f1b.x; a1[5] = (bf16_t)f1b.y; a1[6] = (bf16_t)f1b.z; a1[7] = (bf16_t)f1b.w;
    #pragma unroll
    for (int nt = 0; nt < 8; ++nt) {
      bf16x8 bfrag = Wp[(kt * 8 + nt) * 64 + lane];
      acc[0][nt] = __builtin_amdgcn_mfma_f32_16x16x32_bf16(a0, bfrag, acc[0][nt], 0, 0, 0);
      acc[1][nt] = __builtin_amdgcn_mfma_f32_16x16x32_bf16(a1, bfrag, acc[1][nt], 0, 0, 0);
    }
  }

  #pragma unroll
  for (int mt = 0; mt < 2; ++mt) {
    #pragma unroll
    for (int r = 0; r < 4; ++r) {
      int row = n0 + mt * 16 + q * 4 + r;
      if (row < N) {
        #pragma unroll
        for (int nt = 0; nt < 8; ++nt) {
          int col = nt * 16 + ln;
          Ybf[(size_t)row * 128 + col] = (bf16_t)acc[mt][nt][r];
        }
      }
    }
  }
}

// ---------------------------------------------------------------------------
// Y1 = interp @ Wt1 + pooled0 @ W'  (associativity-fused: featsB never
// materialized; bo0@Wt1 folded into edge-pass-1 bias). Zeroes pooled1;
// pooled0 is preserved for the final kernel.
// ---------------------------------------------------------------------------
__global__ __launch_bounds__(256, 2) void yproj_fused(
    const float* __restrict__ X, const float* __restrict__ pooled0,
    const bf16_t* __restrict__ Wtpk, const bf16_t* __restrict__ Wppk,
    bf16_t* __restrict__ Ybf, float* __restrict__ pooled1, int N)
{
  const int tid = threadIdx.x;
  const int base = blockIdx.x * 128;

  float4 z = make_float4(0.f, 0.f, 0.f, 0.f);
  #pragma unroll
  for (int i = 0; i < 16; ++i) {
    int idx = tid + i * 256;
    int row = base + (idx >> 5);
    if (row < N)
      reinterpret_cast<float4*>(pooled1)[(size_t)row * 32 + (idx & 31)] = z;
  }

  const int lane = tid & 63;
  const int w    = tid >> 6;
  const int q    = lane >> 4;
  const int ln   = lane & 15;
  const int n0   = base + w * 32;

  int r0 = n0 + ln, r1 = n0 + 16 + ln;
  int r0c = (r0 < N) ? r0 : (N - 1);
  int r1c = (r1 < N) ? r1 : (N - 1);
  const float* x0 = X + (size_t)r0c * 128 + q * 8;
  const float* x1 = X + (size_t)r1c * 128 + q * 8;
  const float* p0 = pooled0 + (size_t)r0c * 128 + q * 8;
  const float* p1 = pooled0 + (size_t)r1c * 128 + q * 8;

  f32x4 acc[2][8];
  #pragma unroll
  for (int mt = 0; mt < 2; ++mt)
    #pragma unroll
    for (int nt = 0; nt < 8; ++nt)
      #pragma unroll
      for (int r = 0; r < 4; ++r) acc[mt][nt][r] = 0.f;

  const bf16x8* Wt = reinterpret_cast<const bf16x8*>(Wtpk);
  const bf16x8* Wq = reinterpret_cast<const bf16x8*>(Wppk);
  #pragma unroll
  for (int kt = 0; kt < 4; ++kt) {
    float4 f0a = *reinterpret_cast<const float4*>(x0 + kt * 32);
    float4 f0b = *reinterpret_cast<const float4*>(x0 + kt * 32 + 4);
    float4 f1a = *reinterpret_cast<const float4*>(x1 + kt * 32);
    float4 f1b = *reinterpret_cast<const float4*>(x1 + kt * 32 + 4);
    float4 g0a = *reinterpret_cast<const float4*>(p0 + kt * 32);
    float4 g0b = *reinterpret_cast<const float4*>(p0 + kt * 32 + 4);
    float4 g1a = *reinterpret_cast<const float4*>(p1 + kt * 32);
    float4 g1b = *reinterpret_cast<const float4*>(p1 + kt * 32 + 4);
    bf16x8 a0, a1, b0, b1;
    a0[0] = (bf16_t)f0a.x; a0[1] = (bf16_t)f0a.y; a0[2] = (bf16_t)f0a.z; a0[3] = (bf16_t)f0a.w;
    a0[4] = (bf16_t)f0b.x; a0[5] = (bf16_t)f0b.y; a0[6] = (bf16_t)f0b.z; a0[7] = (bf16_t)f0b.w;
    a1[0] = (bf16_t)f1a.x; a1[1] = (bf16_t)f1a.y; a1[2] = (bf16_t)f1a.z; a1[3] = (bf16_t)f1a.w;
    a1[4] = (bf16_t)f1b.x; a1[5] = (bf16_t)f1b.y; a1[6] = (bf16_t)f1b.z; a1[7] = (bf16_t)f1b.w;
    b0[0] = (bf16_t)g0a.x; b0[1] = (bf16_t)g0a.y; b0[2] = (bf16_t)g0a.z; b0[3] = (bf16_t)g0a.w;
    b0[4] = (bf16_t)g0b.x; b0[5] = (bf16_t)g0b.y; b0[6] = (bf16_t)g0b.z; b0[7] = (bf16_t)g0b.w;
    b1[0] = (bf16_t)g1a.x; b1[1] = (bf16_t)g1a.y; b1[2] = (bf16_t)g1a.z; b1[3] = (bf16_t)g1a.w;
    b1[4] = (bf16_t)g1b.x; b1[5] = (bf16_t)g1b.y; b1[6] = (bf16_t)g1b.z; b1[7] = (bf16_t)g1b.w;
    #pragma unroll
    for (int nt = 0; nt < 8; ++nt) {
      bf16x8 wt = Wt[(kt * 8 + nt) * 64 + lane];
      bf16x8 wq = Wq[(kt * 8 + nt) * 64 + lane];
      acc[0][nt] = __builtin_amdgcn_mfma_f32_16x16x32_bf16(a0, wt, acc[0][nt], 0, 0, 0);
      acc[0][nt] = __builtin_amdgcn_mfma_f32_16x16x32_bf16(b0, wq, acc[0][nt], 0, 0, 0);
      acc[1][nt] = __builtin_amdgcn_mfma_f32_16x16x32_bf16(a1, wt, acc[1][nt], 0, 0, 0);
      acc[1][nt] = __builtin_amdgcn_mfma_f32_16x16x32_bf16(b1, wq, acc[1][nt], 0, 0, 0);
    }
  }

  #pragma unroll
  for (int mt = 0; mt < 2; ++mt) {
    #pragma unroll
    for (int r = 0; r < 4; ++r) {
      int row = n0 + mt * 16 + q * 4 + r;
      if (row < N) {
        #pragma unroll
        for (int nt = 0; nt < 8; ++nt) {
          int col = nt * 16 + ln;
          Ybf[(size_t)row * 128 + col] = (bf16_t)acc[mt][nt][r];
        }
      }
    }
  }
}

// ---------------------------------------------------------------------------
// Edge pass (unchanged from round 11; proven 73 us). Chunk-header vector
// loads + readlane broadcast, packed fp32 math, 4-buffer rotating pipeline.
// ---------------------------------------------------------------------------
__global__ __launch_bounds__(256) void edge_stream(
    const bf16_t* __restrict__ Y,        // N x 128 bf16
    const float* __restrict__ Wb,        // 132 x 128; rows 128..131 = Wbot
    const float* __restrict__ bb,        // 128 (possibly adjusted bias)
    const float* __restrict__ add_info,  // E x 4
    const int* __restrict__ nbr, const int* __restrict__ segs,
    float* __restrict__ pooled, int E)
{
  const int lane = threadIdx.x & 63;
  const int wv = __builtin_amdgcn_readfirstlane(threadIdx.x >> 6);  // SGPR
  const int e0 = (blockIdx.x * 4 + wv) * CH;                        // uniform
  if (e0 >= E) return;
  const int c0 = lane * 2;

  f32x2 wk[4];
  #pragma unroll
  for (int k = 0; k < 4; ++k) {
    wk[k].x = Wb[(size_t)(128 + k) * 128 + c0];
    wk[k].y = Wb[(size_t)(128 + k) * 128 + c0 + 1];
  }
  f32x2 bbv;
  bbv.x = bb[c0]; bbv.y = bb[c0 + 1];

  unsigned* pooled_u = reinterpret_cast<unsigned*>(pooled);
  f32x2 v; v.x = 0.f; v.y = 0.f;

  if (e0 + CH <= E) {
    int v_nbr = nbr[e0 + lane];
    int v_sg  = segs[e0 + lane];
    float v_ai[4];
    #pragma unroll
    for (int r = 0; r < 4; ++r)
      v_ai[r] = add_info[(size_t)e0 * 4 + r * 64 + lane];

    int cur = __builtin_amdgcn_readlane(v_sg, 0);

    unsigned ybuf[4][8];
    #pragma unroll
    for (int p = 0; p < 3; ++p) {
      #pragma unroll
      for (int j = 0; j < 8; ++j) {
        int rn = __builtin_amdgcn_readlane(v_nbr, p * 8 + j);
        ybuf[p][j] = *((const unsigned*)(Y + (size_t)rn * 128) + lane);
      }
    }

    #pragma unroll
    for (int g = 0; g < CH / 8; ++g) {
      if (g + 3 < CH / 8) {
        #pragma unroll
        for (int j = 0; j < 8; ++j) {
          int rn = __builtin_amdgcn_readlane(v_nbr, (g + 3) * 8 + j);
          ybuf[(g + 3) & 3][j] = *((const unsigned*)(Y + (size_t)rn * 128) + lane);
        }
      }
      #pragma unroll
      for (int j = 0; j < 8; ++j) {
        const int i = g * 8 + j;
        int sg = __builtin_amdgcn_readlane(v_sg, i);
        if (sg != cur) {
          if (v.x > 0.f) atomicMax(&pooled_u[(size_t)cur * 128 + c0], __float_as_uint(v.x));
          if (v.y > 0.f) atomicMax(&pooled_u[(size_t)cur * 128 + c0 + 1], __float_as_uint(v.y));
          v.x = 0.f; v.y = 0.f; cur = sg;
        }
        unsigned yb = ybuf[g & 3][j];
        f32x2 y;
        y.x = __uint_as_float(yb << 16);
        y.y = __uint_as_float(yb & 0xffff0000u);
        float a0 = rlf(v_ai[i >> 4], (i * 4 + 0) & 63);
        float a1 = rlf(v_ai[i >> 4], (i * 4 + 1) & 63);
        float a2 = rlf(v_ai[i >> 4], (i * 4 + 2) & 63);
        float a3 = rlf(v_ai[i >> 4], (i * 4 + 3) & 63);
        f32x2 t = bbv + a0 * wk[0];
        t += a1 * wk[1];
        t += a2 * wk[2];
        t += a3 * wk[3];
        t += y;
        v = __builtin_elementwise_max(v, t);
      }
    }
    if (v.x > 0.f) atomicMax(&pooled_u[(size_t)cur * 128 + c0], __float_as_uint(v.x));
    if (v.y > 0.f) atomicMax(&pooled_u[(size_t)cur * 128 + c0 + 1], __float_as_uint(v.y));
  } else {
    int cur = segs[e0];
    const int rem = E - e0;
    for (int i = 0; i < rem; ++i) {
      const int e = e0 + i;
      int sg = segs[e];
      if (sg != cur) {
        if (v.x > 0.f) atomicMax(&pooled_u[(size_t)cur * 128 + c0], __float_as_uint(v.x));
        if (v.y > 0.f) atomicMax(&pooled_u[(size_t)cur * 128 + c0 + 1], __float_as_uint(v.y));
        v.x = 0.f; v.y = 0.f; cur = sg;
      }
      unsigned yb = *reinterpret_cast<const unsigned*>(Y + (size_t)nbr[e] * 128 + c0);
      float y0 = __uint_as_float(yb << 16);
      float y1 = __uint_as_float(yb & 0xffff0000u);
      const float* ai = add_info + (size_t)e * 4;
      float a0 = ai[0], a1 = ai[1], a2 = ai[2], a3 = ai[3];
      float t0 = y0 + bbv.x + a0 * wk[0].x + a1 * wk[1].x + a2 * wk[2].x + a3 * wk[3].x;
      float t1 = y1 + bbv.y + a0 * wk[0].y + a1 * wk[1].y + a2 * wk[2].y + a3 * wk[3].y;
      v.x = fmaxf(v.x, t0);
      v.y = fmaxf(v.y, t1);
    }
    if (v.x > 0.f) atomicMax(&pooled_u[(size_t)cur * 128 + c0], __float_as_uint(v.x));
    if (v.y > 0.f) atomicMax(&pooled_u[(size_t)cur * 128 + c0 + 1], __float_as_uint(v.y));
  }
}

// ---------------------------------------------------------------------------
// out[n] = interp[n].Wf + pooled0[n].wf0' + pooled1[n].wf1' + c
// (associativity-collapsed final; one wave per row, shuffle reduce)
// ---------------------------------------------------------------------------
__global__ __launch_bounds__(256) void final3_kernel(
    const float* __restrict__ X, const float* __restrict__ pooled0,
    const float* __restrict__ pooled1, const float* __restrict__ Wf,
    const float* __restrict__ wf0p, const float* __restrict__ wf1p,
    const float* __restrict__ cp, float* __restrict__ out, int N)
{
  int gtid = blockIdx.x * blockDim.x + threadIdx.x;
  int wave = gtid >> 6;
  int lane = threadIdx.x & 63;
  int nw = (gridDim.x * blockDim.x) >> 6;
  float w0 = Wf[lane],   w1 = Wf[64 + lane];
  float u0 = wf0p[lane], u1 = wf0p[64 + lane];
  float t0 = wf1p[lane], t1 = wf1p[64 + lane];
  float c = cp[0];
  for (int n = wave; n < N; n += nw) {
    const float* xr = X + (size_t)n * 128;
    const float* p0 = pooled0 + (size_t)n * 128;
    const float* p1 = pooled1 + (size_t)n * 128;
    float v = xr[lane] * w0 + xr[64 + lane] * w1
            + p0[lane] * u0 + p0[64 + lane] * u1
            + p1[lane] * t0 + p1[64 + lane] * t1;
    #pragma unroll
    for (int off = 32; off > 0; off >>= 1) v += __shfl_down(v, off);
    if (lane == 0) out[n] = v + c;
  }
}

// ---------------------------------------------------------------------------
extern "C" void kernel_launch(void* const* d_in, const int* in_sizes, int n_in,
                              void* d_out, int out_size, void* d_ws, size_t ws_size,
                              hipStream_t stream)
{
  const float* interpolated = (const float*)d_in[0];
  const float* add_info     = (const float*)d_in[1];
  const int*   nbr          = (const int*)d_in[2];
  const int*   segs         = (const int*)d_in[3];
  const float* Wb0 = (const float*)d_in[4];
  const float* bb0 = (const float*)d_in[5];
  const float* Wo0 = (const float*)d_in[6];
  const float* bo0 = (const float*)d_in[7];
  const float* Wb1 = (const float*)d_in[8];
  const float* bb1 = (const float*)d_in[9];
  const float* Wo1 = (const float*)d_in[10];
  const float* bo1 = (const float*)d_in[11];
  const float* Wf  = (const float*)d_in[12];
  const float* bf_ = (const float*)d_in[13];

  const int N = in_sizes[0] / 128;
  const int E = in_sizes[2];
  float* out = (float*)d_out;

  // workspace layout
  float* pooled0 = (float*)d_ws;                              // N*128 f32
  float* pooled1 = pooled0 + (size_t)N * 128;                 // N*128 f32
  bf16_t* Ybf    = (bf16_t*)(pooled1 + (size_t)N * 128);      // N*128 bf16
  bf16_t* Wt0pk  = Ybf + (size_t)N * 128;                     // 16384
  bf16_t* Wt1pk  = Wt0pk + 16384;
  bf16_t* Wppk   = Wt1pk + 16384;
  float* bb1p    = (float*)(Wppk + 16384);                    // 128
  float* wf0p    = bb1p + 128;                                // 128
  float* wf1p    = wf0p + 128;                                // 128
  float* cp      = wf1p + 128;                                // 1

  const int ugrid = (N + 127) / 128;
  const int egrid = (E + CH * 4 - 1) / (CH * 4);

  PrepArgs pa;
  pa.Wb0 = Wb0; pa.Wb1 = Wb1; pa.Wo0 = Wo0; pa.Wo1 = Wo1; pa.Wf = Wf;
  pa.bb1 = bb1; pa.bo0 = bo0; pa.bo1 = bo1; pa.bf = bf_;
  pa.Wt0pk = Wt0pk; pa.Wt1pk = Wt1pk; pa.Wppk = Wppk;
  pa.bb1p = bb1p; pa.wf0p = wf0p; pa.wf1p = wf1p; pa.cp = cp;
  prep_kernel<<<137, 256, 0, stream>>>(pa);

  // block 0
  yproj_f32<<<ugrid, 256, 0, stream>>>(interpolated, Wt0pk, Ybf, pooled0, N);
  edge_stream<<<egrid, 256, 0, stream>>>(Ybf, Wb0, bb0, add_info, nbr, segs,
                                         pooled0, E);

  // block 1 (fused: Y1 = interp@Wt1 + pooled0@W', bias shift in bb1p)
  yproj_fused<<<ugrid, 256, 0, stream>>>(interpolated, pooled0, Wt1pk, Wppk,
                                         Ybf, pooled1, N);
  edge_stream<<<egrid, 256, 0, stream>>>(Ybf, Wb1, bb1p, add_info, nbr, segs,
                                         pooled1, E);

  // final (collapsed linear chain)
  final3_kernel<<<512, 256, 0, stream>>>(interpolated, pooled0, pooled1,
                                         Wf, wf0p, wf1p, cp, out, N);
}